// Round 5
// baseline (364.169 us; speedup 1.0000x reference)
//
#include <hip/hip_runtime.h>
#include <hip/hip_bf16.h>
#include <stdint.h>

typedef __attribute__((ext_vector_type(8))) short short8;
typedef __attribute__((ext_vector_type(4))) short short4v;
typedef __attribute__((ext_vector_type(4))) float floatx4;
typedef __attribute__((ext_vector_type(2))) float floatx2;
typedef __hip_bfloat16 bf16;

__device__ __forceinline__ float b2f(bf16 v) { return __bfloat162float(v); }
__device__ __forceinline__ bf16 f2b(float v) { return __float2bfloat16(v); }
__device__ __forceinline__ float gelu_f(float v) {
    return 0.5f * v * (1.0f + erff(v * 0.70710678118654752f));
}
// two packed bf16 (one dword) -> two fp32, exact (<<16)
__device__ __forceinline__ floatx2 cvt2(unsigned v) {
    floatx2 r;
    r.x = __uint_as_float(v << 16);
    r.y = __uint_as_float(v & 0xffff0000u);
    return r;
}
// VALU-rate cross-lane add via DPP (no LGKM). CTRL: 0xB1=quad xor1, 0x4E=quad xor2.
template <int CTRL>
__device__ __forceinline__ float dpp_add(float v) {
    int x = __builtin_amdgcn_update_dpp(0, __float_as_int(v), CTRL, 0xf, 0xf, true);
    return v + __int_as_float(x);
}

#define GLD_LDS16(gptr, lptr) \
  __builtin_amdgcn_global_load_lds((const __attribute__((address_space(1))) void*)(gptr), \
                                   (__attribute__((address_space(3))) void*)(lptr), 16, 0, 0)

// NOTE (R12): cooperative grid.sync() costs ~60us each here -- never fuse via grid.sync.
// NOTE (R15): GEMM LDS conflicts: fragment reads, fixed by XOR-swizzled 16B chunks
// (physical slot = logical ^ (row&7)); global_load_lds dest is linear, so swizzle the
// SOURCE k-offset.
// NOTE (R16): x pre-converted to bf16 in k_count_tr; GEMM1 = bf16 global_load_lds path;
// GEMM epilogue in two 64-row halves -> LDS exactly 32 KB.
// NOTE (R17, FAILED): 3-deep gather prefetch added ~12 movs/iter to a VALU-issue-bound
// loop -> 48.6->54.5us. DPP reduce itself is correct and cheaper than shfl.
// NOTE (R18, FAILED): node-grain work-steal = 32768 same-address device atomics at
// ~14ns each = 460us serial wall (VALU 7%). Never fine-grain steal from ONE counter.
// NOTE (R19): 128-thread blocks (max-of-2-waves imbalance) -- only -1.2us; k_agg is
// instruction-issue-bound, not imbalance-bound.
// NOTE (R20): (a) count's atomicAdd return value IS the edge rank -> store it, scatter
// becomes atomic-free (union kernel was scatter-role-bound, masking GEMM gains).
// (b) k_agg 4 edges/iter (16 lanes/edge): per-iter fixed costs amortize 2x, reduce is
// 2 DPP steps (head = one aligned quad).

// ---------------- fused: CSR count+rank (0..511) + weight transposes (512..1535) + x->bf16 (1536..2559) ----------------
__global__ void k_count_tr(const int* __restrict__ dst, int* __restrict__ cnt, int E,
                           const float* __restrict__ Wl1, const float* __restrict__ Wr1,
                           const float* __restrict__ Wl2, const float* __restrict__ Wr2,
                           bf16* __restrict__ Wt,
                           const float* __restrict__ x, bf16* __restrict__ xb,
                           int* __restrict__ rank) {
    int bx = blockIdx.x;
    if (bx < 512) {
        int g = bx * 256 + threadIdx.x;
        if (g * 4 < E) {
            int4 d = ((const int4*)dst)[g];
            int4 rk;
            rk.x = atomicAdd(&cnt[d.x], 1);
            rk.y = atomicAdd(&cnt[d.y], 1);
            rk.z = atomicAdd(&cnt[d.z], 1);
            rk.w = atomicAdd(&cnt[d.w], 1);
            ((int4*)rank)[g] = rk;
        }
    } else if (bx < 1536) {
        int b = bx - 512;
        int r = b & 255, half = (b >> 8) & 1, layer = b >> 9;
        int c = threadIdx.x;
        const float* W = layer ? (half ? Wr2 : Wl2) : (half ? Wr1 : Wl1);
        Wt[(size_t)(layer * 512 + half * 256 + c) * 256 + r] = f2b(W[r * 256 + c]);
    } else {
        // x (32768x256 fp32) -> bf16, 32 contiguous floats per thread
        int b = bx - 1536;
        size_t base = ((size_t)b * 256 + threadIdx.x) * 32;
        const float4* xin = (const float4*)(x + base);
        #pragma unroll
        for (int q = 0; q < 4; q++) {
            float4 a = xin[2 * q];
            float4 c = xin[2 * q + 1];
            bf16 t[8] = {f2b(a.x), f2b(a.y), f2b(a.z), f2b(a.w),
                         f2b(c.x), f2b(c.y), f2b(c.z), f2b(c.w)};
            *(short8*)(xb + base + q * 8) = *(const short8*)t;
        }
    }
}

// n must be 32768: 1024 threads x 32 elements each (int4 loads)
__global__ __launch_bounds__(1024) void k_scan(const int* __restrict__ cnt,
                                               int* __restrict__ row_ptr, int n) {
    __shared__ int sdata[1024];
    int t = threadIdx.x;
    int base = t * 32;
    int local[32];
    const int4* c4 = (const int4*)(cnt + base);
    int vals[32];
    #pragma unroll
    for (int q = 0; q < 8; q++) {
        int4 v = c4[q];
        vals[q * 4 + 0] = v.x; vals[q * 4 + 1] = v.y;
        vals[q * 4 + 2] = v.z; vals[q * 4 + 3] = v.w;
    }
    int sum = 0;
    #pragma unroll
    for (int k = 0; k < 32; k++) { local[k] = sum; sum += vals[k]; }
    sdata[t] = sum;
    __syncthreads();
    for (int off = 1; off < 1024; off <<= 1) {
        int v = (t >= off) ? sdata[t - off] : 0;
        __syncthreads();
        sdata[t] += v;
        __syncthreads();
    }
    int excl = sdata[t] - sum;
    #pragma unroll
    for (int k = 0; k < 32; k++)
        row_ptr[base + k] = excl + local[k];
    if (t == 1023) row_ptr[n] = excl + sum;
}

// ---------------- GEMM tile body: C[M,512] = A[M,K] @ Bt[512,K]^T + bias ----------------
// 128x128 tile, BK=64, XOR-swizzled LDS (physical 16B chunk = logical ^ (row&7)).
// bf16 A only (global_load_lds both operands). LDS = 32768 B exactly (5 blocks/CU).
__device__ __forceinline__ void gemm_body(const bf16* __restrict__ A,
                                          const bf16* __restrict__ Bt,
                                          const float* __restrict__ biasL,
                                          const float* __restrict__ biasR,
                                          bf16* __restrict__ C,
                                          int K, int m0, int n0,
                                          bf16* __restrict__ smem) {
    bf16* As = smem;
    bf16* Bs = smem + 8192;
    const int tid  = threadIdx.x;
    const int wave = tid >> 6;
    const int lane = tid & 63;
    const int quad = lane >> 4;
    const int l16  = lane & 15;
    const int wm = (wave & 1) * 64;
    const int wn = (wave >> 1) * 64;
    // source k-offset for swizzled global_load_lds staging (dest slot lane&7, row lane>>3)
    const int scole = ((lane & 7) ^ (lane >> 3)) * 8;
    const int srow  = lane >> 3;

    floatx4 acc[4][4] = {};

    for (int k0 = 0; k0 < K; k0 += 64) {
        #pragma unroll
        for (int i = 0; i < 4; i++) {
            int chunk = i * 4 + wave;                 // 16 chunks of 1 KB (8 rows) each
            int row = chunk * 8 + srow;
            GLD_LDS16(A + (size_t)(m0 + row) * K + k0 + scole,
                      (char*)As + chunk * 1024 + lane * 16);
            GLD_LDS16(Bt + (size_t)(n0 + row) * K + k0 + scole,
                      (char*)Bs + chunk * 1024 + lane * 16);
        }
        __syncthreads();
        #pragma unroll
        for (int ks = 0; ks < 2; ks++) {
            short8 af[4], bfr[4];
            int pk = ((ks * 4 + quad) ^ (l16 & 7)) * 8;   // swizzled fragment k-offset
            #pragma unroll
            for (int i = 0; i < 4; i++) {
                af[i]  = *(const short8*)&As[(wm + i * 16 + l16) * 64 + pk];
                bfr[i] = *(const short8*)&Bs[(wn + i * 16 + l16) * 64 + pk];
            }
            #pragma unroll
            for (int i = 0; i < 4; i++)
                #pragma unroll
                for (int j = 0; j < 4; j++)
                    acc[i][j] = __builtin_amdgcn_mfma_f32_16x16x32_bf16(af[i], bfr[j], acc[i][j], 0, 0, 0);
        }
        __syncthreads();
    }

    // C/D layout: col = lane&15, row = quad*4 + reg  [verified m89/m91]
    // Two 64-row halves through a 64x136 LDS buffer (fits in As+Bs region).
    float bvj[4];
    #pragma unroll
    for (int j = 0; j < 4; j++) {
        int gcol = n0 + wn + j * 16 + l16;
        bvj[j] = (gcol < 256) ? biasL[gcol] : biasR[gcol - 256];
    }
    #pragma unroll
    for (int h = 0; h < 2; h++) {
        if ((wave & 1) == h) {
            #pragma unroll
            for (int j = 0; j < 4; j++) {
                int lcol = wn + j * 16 + l16;
                #pragma unroll
                for (int i = 0; i < 4; i++)
                    #pragma unroll
                    for (int r = 0; r < 4; r++)
                        smem[(i * 16 + quad * 4 + r) * 136 + lcol] = f2b(acc[i][j][r] + bvj[j]);
            }
        }
        __syncthreads();
        {
            int rl = tid >> 4;
            int cs = (tid & 15) * 8;
            #pragma unroll
            for (int p = 0; p < 4; p++) {
                int row = p * 16 + rl;
                short8 v = *(const short8*)&smem[row * 136 + cs];
                *(short8*)(C + (size_t)(m0 + h * 64 + row) * 512 + n0 + cs) = v;
            }
        }
        if (h == 0) __syncthreads();
    }
}

// ---------------- union dispatch: scatter (atomic-free) + layer-1 GEMM ----------------
__global__ __launch_bounds__(256) void k_scatter_gemm(const int* __restrict__ src,
                                                      const int* __restrict__ dst,
                                                      const int* __restrict__ row_ptr,
                                                      const int* __restrict__ rank,
                                                      int* __restrict__ col, int E,
                                                      const bf16* __restrict__ A,
                                                      const bf16* __restrict__ Bt,
                                                      const float* __restrict__ biasL,
                                                      const float* __restrict__ biasR,
                                                      bf16* __restrict__ C, int K) {
    __shared__ bf16 smem[16384];
    int bx = blockIdx.x;
    int rem = bx % 3;
    if (rem == 2) {
        int g = (bx / 3) * 256 + threadIdx.x;
        if (g * 4 < E) {
            int4 d = ((const int4*)dst)[g];
            int4 sv = ((const int4*)src)[g];
            int4 rk = ((const int4*)rank)[g];
            col[row_ptr[d.x] + rk.x] = sv.x;
            col[row_ptr[d.y] + rk.y] = sv.y;
            col[row_ptr[d.z] + rk.z] = sv.z;
            col[row_ptr[d.w] + rk.w] = sv.w;
        }
    } else {
        int gid = (bx / 3) * 2 + rem;
        int n0 = (gid & 3) * 128;
        int m0 = (gid >> 2) * 128;
        gemm_body(A, Bt, biasL, biasR, C, K, m0, n0, smem);
    }
}

// ---------------- standalone GEMM (layer 2, bf16 A) ----------------
__global__ __launch_bounds__(256) void k_gemm2(const bf16* __restrict__ A,
                                               const bf16* __restrict__ Bt,
                                               const float* __restrict__ biasL,
                                               const float* __restrict__ biasR,
                                               bf16* __restrict__ C, int K) {
    __shared__ bf16 smem[16384];
    int n0 = blockIdx.x * 128;
    int m0 = blockIdx.y * 128;
    gemm_body(A, Bt, biasL, biasR, C, K, m0, n0, smem);
}

// ---------------- GATv2 aggregation: 4 edges/iter, 16 lanes/edge, 16 ch/lane ----------
// 128-thread blocks, one wave per dst node. Lane = q*16 + r: q = edge slot (0..3),
// head = r>>2 (one aligned quad per head), ch = (r>>2)*64 + (r&3)*16 .. +16.
// Item 0 = self-loop. Max-free softmax (logits bounded), leaky = 0.6u + 0.4|u| folded
// into att. Logit reduce = 2 DPP quad-perm adds; slot combine = shfl_xor 16/32.
__global__ __launch_bounds__(128) void k_agg(const bf16* __restrict__ xlr,
                                             const float* __restrict__ att,
                                             const int* __restrict__ row_ptr,
                                             const int* __restrict__ col,
                                             const float* __restrict__ bias,
                                             bf16* __restrict__ out, int do_gelu) {
    int wave = threadIdx.x >> 6, lane = threadIdx.x & 63;
    int i = blockIdx.x * 2 + wave;
    int q = lane >> 4;           // edge slot
    int r = lane & 15;
    unsigned f = (unsigned)(r >> 2) * 64 + (unsigned)(r & 3) * 16;  // 16 ch per lane

    floatx2 att6v[8], att4v[8], xrv[8];
    #pragma unroll
    for (int k = 0; k < 4; k++) {
        floatx4 a = *(const floatx4*)(att + f + 4 * k);
        att6v[2 * k]     = (floatx2){0.6f * a[0], 0.6f * a[1]};
        att6v[2 * k + 1] = (floatx2){0.6f * a[2], 0.6f * a[3]};
        att4v[2 * k]     = (floatx2){0.4f * a[0], 0.4f * a[1]};
        att4v[2 * k + 1] = (floatx2){0.4f * a[2], 0.4f * a[3]};
    }
    {
        unsigned raw[8];
        *(uint4*)raw       = *(const uint4*)(xlr + ((unsigned)i * 512u + 256u + f));
        *(uint4*)(raw + 4) = *(const uint4*)(xlr + ((unsigned)i * 512u + 256u + f + 8));
        #pragma unroll
        for (int k = 0; k < 8; k++) xrv[k] = cvt2(raw[k]);
    }

    int e0 = row_ptr[i], e1 = row_ptr[i + 1];
    int total = 1 + (e1 - e0);   // self + in-edges

    // item t = base + q; t==0 is the self-loop
    int src_c = (q > 0 && q < total) ? col[e0 + q - 1] : i;
    unsigned g_cur[8], g_nxt[8];
    *(uint4*)g_cur       = *(const uint4*)(xlr + ((unsigned)src_c * 512u + f));
    *(uint4*)(g_cur + 4) = *(const uint4*)(xlr + ((unsigned)src_c * 512u + f + 8));
    int t1 = 4 + q;
    int src_n = (t1 < total) ? col[e0 + t1 - 1] : i;

    float s = 0.f;
    floatx2 acc2[8] = {};

    for (int base = 0; base < total; base += 4) {
        *(uint4*)g_nxt       = *(const uint4*)(xlr + ((unsigned)src_n * 512u + f));
        *(uint4*)(g_nxt + 4) = *(const uint4*)(xlr + ((unsigned)src_n * 512u + f + 8));
        int t2 = base + 8 + q;
        int src_n2 = (t2 < total) ? col[e0 + t2 - 1] : i;
        bool valid = (base + q) < total;
        floatx2 xv[8], l2a = {0.f, 0.f}, l2b = {0.f, 0.f};
        #pragma unroll
        for (int k = 0; k < 8; k++) {
            xv[k] = cvt2(g_cur[k]);
            floatx2 u = xv[k] + xrv[k];           // v_pk_add_f32
            floatx2 au = __builtin_elementwise_abs(u);
            l2a += u * att6v[k];                  // v_pk_fma_f32
            l2b += au * att4v[k];                 // v_pk_fma_f32
        }
        float l = (l2a.x + l2b.x) + (l2a.y + l2b.y);
        l = dpp_add<0xB1>(l);     // xor1 within quad
        l = dpp_add<0x4E>(l);     // xor2 within quad -> full 64-ch head logit
        float p = valid ? __expf(l) : 0.f;
        s += p;
        floatx2 p2 = {p, p};
        #pragma unroll
        for (int k = 0; k < 8; k++) acc2[k] += p2 * xv[k];   // v_pk_fma_f32
        #pragma unroll
        for (int k = 0; k < 8; k++) g_cur[k] = g_nxt[k];
        src_n = src_n2;
    }

    // combine the 4 edge slots
    s += __shfl_xor(s, 16, 64);
    s += __shfl_xor(s, 32, 64);
    #pragma unroll
    for (int k = 0; k < 8; k++) {
        acc2[k].x += __shfl_xor(acc2[k].x, 16, 64);
        acc2[k].x += __shfl_xor(acc2[k].x, 32, 64);
        acc2[k].y += __shfl_xor(acc2[k].y, 16, 64);
        acc2[k].y += __shfl_xor(acc2[k].y, 32, 64);
    }

    if (q == 0) {
        float inv = 1.0f / (s + 1e-16f);
        bf16 ov[16];
        #pragma unroll
        for (int k = 0; k < 8; k++) {
            float v0 = acc2[k].x * inv + bias[f + 2 * k];
            float v1 = acc2[k].y * inv + bias[f + 2 * k + 1];
            if (do_gelu) { v0 = gelu_f(v0); v1 = gelu_f(v1); }
            ov[2 * k]     = f2b(v0);
            ov[2 * k + 1] = f2b(v1);
        }
        *(short8*)(out + ((unsigned)i * 256u + f))     = *(const short8*)ov;
        *(short8*)(out + ((unsigned)i * 256u + f + 8)) = *(const short8*)(ov + 8);
    }
}

// ---------------- shared head-layer body (block = one (graph, 64-col chunk)) ----------------
__device__ __forceinline__ void head_body(const bf16* __restrict__ inB,
                                          const float* __restrict__ inF,
                                          const float* __restrict__ W,
                                          const float* __restrict__ bias,
                                          float* __restrict__ out,
                                          int K, int N, long long row_stride, int act,
                                          int g, int chunk, float* zin, float* red) {
    int t = threadIdx.x;
    int nc = t & 63;
    int kq = t >> 6;
    int n = chunk * 64 + nc;
    for (int k = t; k < K; k += 256)
        zin[k] = inB ? b2f(inB[(size_t)g * row_stride + k])
                     : inF[(size_t)g * row_stride + k];
    __syncthreads();
    const int klen = K >> 2;
    const int kb = kq * klen;
    float acc = 0.f;
    #pragma unroll 8
    for (int k = 0; k < klen; k++)
        acc = fmaf(zin[kb + k], W[(size_t)(kb + k) * N + n], acc);
    red[t] = acc;
    __syncthreads();
    if (kq == 0) {
        float v = red[nc] + red[nc + 64] + red[nc + 128] + red[nc + 192] + bias[n];
        if (act) v = gelu_f(v);
        out[(size_t)g * N + n] = v;
    }
}

// ---------------- fused: pool stage 1 (blocks 0..511) + head lin1 (512..1535) ----------------
__global__ __launch_bounds__(256) void k_pe1(const bf16* __restrict__ hb,
                                             float* __restrict__ part,
                                             const float* __restrict__ lin1w,
                                             const float* __restrict__ lin1b,
                                             float* __restrict__ t1, int PG) {
    __shared__ float zin[256];
    __shared__ float red[256];
    int bx = blockIdx.x;
    if (bx < 512) {
        int g = bx >> 3, p = bx & 7, c = threadIdx.x;
        int rows_per = PG / 8;
        const bf16* base = hb + ((size_t)g * PG + (size_t)p * rows_per) * 256;
        float acc = 0.f;
        for (int r = 0; r < rows_per; r++) acc += b2f(base[(size_t)r * 256 + c]);
        part[((size_t)g * 8 + p) * 256 + c] = acc;
    } else {
        int b = bx - 512;
        head_body(hb, nullptr, lin1w, lin1b, t1, 256, 1024,
                  (long long)PG * 256, 1, b >> 4, b & 15, zin, red);
    }
}

// ---------------- fused: pool stage 2 (blocks 0..63) + head lin2 (64..319) ----------------
__global__ __launch_bounds__(256) void k_pe2(const float* __restrict__ part,
                                             float* __restrict__ outPool, int PG,
                                             const float* __restrict__ t1,
                                             const float* __restrict__ lin2w,
                                             const float* __restrict__ lin2b,
                                             float* __restrict__ t2) {
    __shared__ float zin[1024];
    __shared__ float red[256];
    int bx = blockIdx.x;
    if (bx < 64) {
        int g = bx, c = threadIdx.x;
        float acc = 0.f;
        for (int p = 0; p < 8; p++) acc += part[((size_t)g * 8 + p) * 256 + c];
        outPool[g * 256 + c] = acc / (float)PG;
    } else {
        int b = bx - 64;
        head_body(nullptr, t1, lin2w, lin2b, t2, 1024, 256,
                  1024, 0, b >> 2, b & 3, zin, red);
    }
}

// ---------------- final head layer ----------------
__global__ __launch_bounds__(256) void k_fin(const float* __restrict__ t2,
                                             const float* __restrict__ finw,
                                             const float* __restrict__ finb,
                                             float* __restrict__ out) {
    __shared__ float zin[256];
    __shared__ float red[256];
    head_body(nullptr, t2, finw, finb, out, 256, 512,
              256, 0, blockIdx.x, blockIdx.y, zin, red);
}

extern "C" void kernel_launch(void* const* d_in, const int* in_sizes, int n_in,
                              void* d_out, int out_size, void* d_ws, size_t ws_size,
                              hipStream_t stream) {
    const float* x     = (const float*)d_in[0];
    const int*   ei    = (const int*)d_in[1];
    const float* w1_l  = (const float*)d_in[4];
    const float* b1_l  = (const float*)d_in[5];
    const float* w1_r  = (const float*)d_in[6];
    const float* b1_r  = (const float*)d_in[7];
    const float* att1  = (const float*)d_in[8];
    const float* bias1 = (const float*)d_in[9];
    const float* w2_l  = (const float*)d_in[10];
    const float* b2_l  = (const float*)d_in[11];
    const float* w2_r  = (const float*)d_in[12];
    const float* b2_r  = (const float*)d_in[13];
    const float* att2  = (const float*)d_in[14];
    const float* bias2 = (const float*)d_in[15];
    const float* lin1w = (const float*)d_in[16];
    const float* lin1b = (const float*)d_in[17];
    const float* lin2w = (const float*)d_in[18];
    const float* lin2b = (const float*)d_in[19];
    const float* finw  = (const float*)d_in[20];
    const float* finb  = (const float*)d_in[21];

    const int N  = in_sizes[0] / 256;   // 32768
    const int E  = in_sizes[1] / 2;     // 524288
    const int NG = 64;
    const int PG = N / NG;              // 512

    // workspace layout (~54.5 MiB)
    char* ws = (char*)d_ws;
    size_t off = 0;
    bf16* xlr = (bf16*)(ws + off); off += (size_t)N * 512 * 2;    // 32 MiB [xl|xr]
    bf16* hb  = (bf16*)(ws + off); off += (size_t)N * 256 * 2;    // 16 MiB (h1 then h2)
    bf16* wt  = (bf16*)(ws + off); off += 2 * 512 * 256 * 2;      // 512 KiB both layers' Wt
    int* row_ptr = (int*)(ws + off); off += (size_t)(N + 4) * 4;
    int* cnt     = (int*)(ws + off); off += (size_t)N * 4;
    int* col     = (int*)(ws + off); off += (size_t)E * 4;
    int* rank    = (int*)(ws + off); off += (size_t)E * 4;        // edge rank within dst
    float* pws   = (float*)(ws + off); off += (size_t)NG * 8 * 256 * 4;  // pool partials
    float* t1    = (float*)(ws + off); off += (size_t)NG * 1024 * 4;
    float* t2    = (float*)(ws + off); off += (size_t)NG * 256 * 4;

    // bf16 copy of x aliases hb: dead until k_agg writes h1 (strictly after GEMM1 reads xb)
    bf16* xb = hb;

    const int* srcv = ei;
    const int* dstv = ei + E;

    // --- CSR count+rank + weight transposes + x->bf16 (one launch) ---
    hipMemsetAsync(cnt, 0, (size_t)N * 4, stream);
    k_count_tr<<<512 + 1024 + 1024, 256, 0, stream>>>(dstv, cnt, E,
                                                      w1_l, w1_r, w2_l, w2_r, wt, x, xb,
                                                      rank);
    k_scan<<<1, 1024, 0, stream>>>(cnt, row_ptr, N);

    // --- scatter (atomic-free) + layer-1 GEMM (one union launch) ---
    k_scatter_gemm<<<512 + 1024, 256, 0, stream>>>(srcv, dstv, row_ptr, rank, col, E,
                                                   xb, wt, b1_l, b1_r, xlr, 256);
    k_agg<<<N / 2, 128, 0, stream>>>(xlr, att1, row_ptr, col, bias1, hb, 1);  // + GELU

    // --- layer 2 (A = h1 bf16) ---
    dim3 gg(4, N / 128);
    k_gemm2<<<gg, 256, 0, stream>>>(hb, wt + 512 * 256, b2_l, b2_r, xlr, 256);
    k_agg<<<N / 2, 128, 0, stream>>>(xlr, att2, row_ptr, col, bias2, hb, 0);  // h2

    float* outp = (float*)d_out;
    // --- pool1 + head lin1 (one launch) ---
    k_pe1<<<512 + 1024, 256, 0, stream>>>(hb, pws, lin1w, lin1b, t1, PG);
    // --- pool2 (-> d_out[64*512..]) + head lin2 (one launch) ---
    k_pe2<<<64 + 256, 256, 0, stream>>>(pws, outp + 64 * 512, PG, t1, lin2w, lin2b, t2);
    // --- final head layer -> d_out[0..64*512) ---
    dim3 gf(NG, 512 / 64);
    k_fin<<<gf, 256, 0, stream>>>(t2, finw, finb, outp);
}

// Round 6
// 322.787 us; speedup vs baseline: 1.1282x; 1.1282x over previous
//
#include <hip/hip_runtime.h>
#include <hip/hip_bf16.h>
#include <stdint.h>

typedef __attribute__((ext_vector_type(8))) short short8;
typedef __attribute__((ext_vector_type(4))) short short4v;
typedef __attribute__((ext_vector_type(4))) float floatx4;
typedef __attribute__((ext_vector_type(2))) float floatx2;
typedef __hip_bfloat16 bf16;

__device__ __forceinline__ float b2f(bf16 v) { return __bfloat162float(v); }
__device__ __forceinline__ bf16 f2b(float v) { return __float2bfloat16(v); }
__device__ __forceinline__ float gelu_f(float v) {
    return 0.5f * v * (1.0f + erff(v * 0.70710678118654752f));
}
// two packed bf16 (one dword) -> two fp32, exact (<<16)
__device__ __forceinline__ floatx2 cvt2(unsigned v) {
    floatx2 r;
    r.x = __uint_as_float(v << 16);
    r.y = __uint_as_float(v & 0xffff0000u);
    return r;
}
// VALU-rate cross-lane add via DPP (no LGKM). CTRL: 0xB1=quad xor1, 0x4E=quad xor2,
// 0x141=row_half_mirror (cross-quad within 8-lane group; groups are 8-aligned).
template <int CTRL>
__device__ __forceinline__ float dpp_add(float v) {
    int x = __builtin_amdgcn_update_dpp(0, __float_as_int(v), CTRL, 0xf, 0xf, true);
    return v + __int_as_float(x);
}

#define GLD_LDS16(gptr, lptr) \
  __builtin_amdgcn_global_load_lds((const __attribute__((address_space(1))) void*)(gptr), \
                                   (__attribute__((address_space(3))) void*)(lptr), 16, 0, 0)

// NOTE (R12): cooperative grid.sync() costs ~60us each here -- never fuse via grid.sync.
// NOTE (R15): GEMM LDS conflicts: fragment reads, fixed by XOR-swizzled 16B chunks
// (physical slot = logical ^ (row&7)); global_load_lds dest is linear, so swizzle the
// SOURCE k-offset.
// NOTE (R16): x pre-converted to bf16 in k_count_tr; GEMM1 = bf16 global_load_lds path;
// GEMM epilogue in two 64-row halves -> LDS exactly 32 KB.
// NOTE (R17, FAILED): 3-deep gather prefetch added ~12 movs/iter -> slower. No added
// per-lane state in the k_agg loop.
// NOTE (R18, FAILED): node-grain work-steal = 32768 same-address atomics = 460us wall.
// NOTE (R19): 128-thread blocks; k_agg is instruction-issue-bound (VALU 76%).
// NOTE (R20a): count's atomicAdd return value IS the edge rank -> scatter is atomic-free
// (rank stored in k_count_tr); non-k_agg pipeline improved ~8us. KEEP.
// NOTE (R20b, FAILED): 16 lanes/edge doubled per-lane regs (VGPR 56) -> occupancy
// 65->38%, halved cross-iter ILP -> 66us. Confirmed: loop tolerates no extra state.
// NOTE (R21): back to R19 shape + lrelu=max(u,0.2u) (saves ops + 8 VGPR vs 0.6/0.4|u|
// trick) + att pre-scaled by log2e so p=v_exp_f32(l) directly (saves the __expf mul).

// ---------------- fused: CSR count+rank (0..511) + weight transposes (512..1535) + x->bf16 (1536..2559) ----------------
__global__ void k_count_tr(const int* __restrict__ dst, int* __restrict__ cnt, int E,
                           const float* __restrict__ Wl1, const float* __restrict__ Wr1,
                           const float* __restrict__ Wl2, const float* __restrict__ Wr2,
                           bf16* __restrict__ Wt,
                           const float* __restrict__ x, bf16* __restrict__ xb,
                           int* __restrict__ rank) {
    int bx = blockIdx.x;
    if (bx < 512) {
        int g = bx * 256 + threadIdx.x;
        if (g * 4 < E) {
            int4 d = ((const int4*)dst)[g];
            int4 rk;
            rk.x = atomicAdd(&cnt[d.x], 1);
            rk.y = atomicAdd(&cnt[d.y], 1);
            rk.z = atomicAdd(&cnt[d.z], 1);
            rk.w = atomicAdd(&cnt[d.w], 1);
            ((int4*)rank)[g] = rk;
        }
    } else if (bx < 1536) {
        int b = bx - 512;
        int r = b & 255, half = (b >> 8) & 1, layer = b >> 9;
        int c = threadIdx.x;
        const float* W = layer ? (half ? Wr2 : Wl2) : (half ? Wr1 : Wl1);
        Wt[(size_t)(layer * 512 + half * 256 + c) * 256 + r] = f2b(W[r * 256 + c]);
    } else {
        // x (32768x256 fp32) -> bf16, 32 contiguous floats per thread
        int b = bx - 1536;
        size_t base = ((size_t)b * 256 + threadIdx.x) * 32;
        const float4* xin = (const float4*)(x + base);
        #pragma unroll
        for (int q = 0; q < 4; q++) {
            float4 a = xin[2 * q];
            float4 c = xin[2 * q + 1];
            bf16 t[8] = {f2b(a.x), f2b(a.y), f2b(a.z), f2b(a.w),
                         f2b(c.x), f2b(c.y), f2b(c.z), f2b(c.w)};
            *(short8*)(xb + base + q * 8) = *(const short8*)t;
        }
    }
}

// n must be 32768: 1024 threads x 32 elements each (int4 loads)
__global__ __launch_bounds__(1024) void k_scan(const int* __restrict__ cnt,
                                               int* __restrict__ row_ptr, int n) {
    __shared__ int sdata[1024];
    int t = threadIdx.x;
    int base = t * 32;
    int local[32];
    const int4* c4 = (const int4*)(cnt + base);
    int vals[32];
    #pragma unroll
    for (int q = 0; q < 8; q++) {
        int4 v = c4[q];
        vals[q * 4 + 0] = v.x; vals[q * 4 + 1] = v.y;
        vals[q * 4 + 2] = v.z; vals[q * 4 + 3] = v.w;
    }
    int sum = 0;
    #pragma unroll
    for (int k = 0; k < 32; k++) { local[k] = sum; sum += vals[k]; }
    sdata[t] = sum;
    __syncthreads();
    for (int off = 1; off < 1024; off <<= 1) {
        int v = (t >= off) ? sdata[t - off] : 0;
        __syncthreads();
        sdata[t] += v;
        __syncthreads();
    }
    int excl = sdata[t] - sum;
    #pragma unroll
    for (int k = 0; k < 32; k++)
        row_ptr[base + k] = excl + local[k];
    if (t == 1023) row_ptr[n] = excl + sum;
}

// ---------------- GEMM tile body: C[M,512] = A[M,K] @ Bt[512,K]^T + bias ----------------
// 128x128 tile, BK=64, XOR-swizzled LDS (physical 16B chunk = logical ^ (row&7)).
// bf16 A only (global_load_lds both operands). LDS = 32768 B exactly (5 blocks/CU).
__device__ __forceinline__ void gemm_body(const bf16* __restrict__ A,
                                          const bf16* __restrict__ Bt,
                                          const float* __restrict__ biasL,
                                          const float* __restrict__ biasR,
                                          bf16* __restrict__ C,
                                          int K, int m0, int n0,
                                          bf16* __restrict__ smem) {
    bf16* As = smem;
    bf16* Bs = smem + 8192;
    const int tid  = threadIdx.x;
    const int wave = tid >> 6;
    const int lane = tid & 63;
    const int quad = lane >> 4;
    const int l16  = lane & 15;
    const int wm = (wave & 1) * 64;
    const int wn = (wave >> 1) * 64;
    // source k-offset for swizzled global_load_lds staging (dest slot lane&7, row lane>>3)
    const int scole = ((lane & 7) ^ (lane >> 3)) * 8;
    const int srow  = lane >> 3;

    floatx4 acc[4][4] = {};

    for (int k0 = 0; k0 < K; k0 += 64) {
        #pragma unroll
        for (int i = 0; i < 4; i++) {
            int chunk = i * 4 + wave;                 // 16 chunks of 1 KB (8 rows) each
            int row = chunk * 8 + srow;
            GLD_LDS16(A + (size_t)(m0 + row) * K + k0 + scole,
                      (char*)As + chunk * 1024 + lane * 16);
            GLD_LDS16(Bt + (size_t)(n0 + row) * K + k0 + scole,
                      (char*)Bs + chunk * 1024 + lane * 16);
        }
        __syncthreads();
        #pragma unroll
        for (int ks = 0; ks < 2; ks++) {
            short8 af[4], bfr[4];
            int pk = ((ks * 4 + quad) ^ (l16 & 7)) * 8;   // swizzled fragment k-offset
            #pragma unroll
            for (int i = 0; i < 4; i++) {
                af[i]  = *(const short8*)&As[(wm + i * 16 + l16) * 64 + pk];
                bfr[i] = *(const short8*)&Bs[(wn + i * 16 + l16) * 64 + pk];
            }
            #pragma unroll
            for (int i = 0; i < 4; i++)
                #pragma unroll
                for (int j = 0; j < 4; j++)
                    acc[i][j] = __builtin_amdgcn_mfma_f32_16x16x32_bf16(af[i], bfr[j], acc[i][j], 0, 0, 0);
        }
        __syncthreads();
    }

    // C/D layout: col = lane&15, row = quad*4 + reg  [verified m89/m91]
    // Two 64-row halves through a 64x136 LDS buffer (fits in As+Bs region).
    float bvj[4];
    #pragma unroll
    for (int j = 0; j < 4; j++) {
        int gcol = n0 + wn + j * 16 + l16;
        bvj[j] = (gcol < 256) ? biasL[gcol] : biasR[gcol - 256];
    }
    #pragma unroll
    for (int h = 0; h < 2; h++) {
        if ((wave & 1) == h) {
            #pragma unroll
            for (int j = 0; j < 4; j++) {
                int lcol = wn + j * 16 + l16;
                #pragma unroll
                for (int i = 0; i < 4; i++)
                    #pragma unroll
                    for (int r = 0; r < 4; r++)
                        smem[(i * 16 + quad * 4 + r) * 136 + lcol] = f2b(acc[i][j][r] + bvj[j]);
            }
        }
        __syncthreads();
        {
            int rl = tid >> 4;
            int cs = (tid & 15) * 8;
            #pragma unroll
            for (int p = 0; p < 4; p++) {
                int row = p * 16 + rl;
                short8 v = *(const short8*)&smem[row * 136 + cs];
                *(short8*)(C + (size_t)(m0 + h * 64 + row) * 512 + n0 + cs) = v;
            }
        }
        if (h == 0) __syncthreads();
    }
}

// ---------------- union dispatch: scatter (atomic-free) + layer-1 GEMM ----------------
__global__ __launch_bounds__(256) void k_scatter_gemm(const int* __restrict__ src,
                                                      const int* __restrict__ dst,
                                                      const int* __restrict__ row_ptr,
                                                      const int* __restrict__ rank,
                                                      int* __restrict__ col, int E,
                                                      const bf16* __restrict__ A,
                                                      const bf16* __restrict__ Bt,
                                                      const float* __restrict__ biasL,
                                                      const float* __restrict__ biasR,
                                                      bf16* __restrict__ C, int K) {
    __shared__ bf16 smem[16384];
    int bx = blockIdx.x;
    int rem = bx % 3;
    if (rem == 2) {
        int g = (bx / 3) * 256 + threadIdx.x;
        if (g * 4 < E) {
            int4 d = ((const int4*)dst)[g];
            int4 sv = ((const int4*)src)[g];
            int4 rk = ((const int4*)rank)[g];
            col[row_ptr[d.x] + rk.x] = sv.x;
            col[row_ptr[d.y] + rk.y] = sv.y;
            col[row_ptr[d.z] + rk.z] = sv.z;
            col[row_ptr[d.w] + rk.w] = sv.w;
        }
    } else {
        int gid = (bx / 3) * 2 + rem;
        int n0 = (gid & 3) * 128;
        int m0 = (gid >> 2) * 128;
        gemm_body(A, Bt, biasL, biasR, C, K, m0, n0, smem);
    }
}

// ---------------- standalone GEMM (layer 2, bf16 A) ----------------
__global__ __launch_bounds__(256) void k_gemm2(const bf16* __restrict__ A,
                                               const bf16* __restrict__ Bt,
                                               const float* __restrict__ biasL,
                                               const float* __restrict__ biasR,
                                               bf16* __restrict__ C, int K) {
    __shared__ bf16 smem[16384];
    int n0 = blockIdx.x * 128;
    int m0 = blockIdx.y * 128;
    gemm_body(A, Bt, biasL, biasR, C, K, m0, n0, smem);
}

// ---------------- GATv2 aggregation: half-wave per edge, 8 ch/lane, packed fp32 math ----------
// 128-thread blocks, one wave per dst node. Lanes 0-31 = item a, 32-63 = item b of each
// pair. Within a half: 8 lanes per head (hl>>3), 8 channels per lane ((hl&7)*8).
// Item 0 = self-loop. Max-free softmax (logits bounded). R21: leaky = max(u, 0.2u),
// att pre-scaled by log2(e) so p = v_exp_f32(l) = e^logit directly.
// Reduce via DPP (quad xor1, xor2, half-mirror) at VALU rate.
__global__ __launch_bounds__(128) void k_agg(const bf16* __restrict__ xlr,
                                             const float* __restrict__ att,
                                             const int* __restrict__ row_ptr,
                                             const int* __restrict__ col,
                                             const float* __restrict__ bias,
                                             bf16* __restrict__ out, int do_gelu) {
    int wave = threadIdx.x >> 6, lane = threadIdx.x & 63;
    int i = blockIdx.x * 2 + wave;
    int hl = lane & 31;
    int half = lane >> 5;
    unsigned f = (hl >> 3) * 64 + (hl & 7) * 8;

    const float LOG2E = 1.4426950408889634f;
    const floatx2 c02 = {0.2f, 0.2f};
    floatx2 attv[4], xrv[4];
    {
        floatx4 a0 = *(const floatx4*)(att + f);
        floatx4 a1 = *(const floatx4*)(att + f + 4);
        attv[0] = (floatx2){LOG2E * a0[0], LOG2E * a0[1]};
        attv[1] = (floatx2){LOG2E * a0[2], LOG2E * a0[3]};
        attv[2] = (floatx2){LOG2E * a1[0], LOG2E * a1[1]};
        attv[3] = (floatx2){LOG2E * a1[2], LOG2E * a1[3]};
        unsigned raw[4];
        *(uint4*)raw = *(const uint4*)(xlr + ((unsigned)i * 512u + 256u + f));
        #pragma unroll
        for (int k = 0; k < 4; k++) xrv[k] = cvt2(raw[k]);
    }

    int e0 = row_ptr[i], e1 = row_ptr[i + 1];
    int total = 1 + (e1 - e0);   // self + in-edges

    int src_c = i;
    if (half == 1 && total > 1) src_c = col[e0];
    unsigned g_cur[4];
    *(uint4*)g_cur = *(const uint4*)(xlr + ((unsigned)src_c * 512u + f));
    int t1 = 2 + half;
    int src_n = (t1 < total) ? col[e0 + t1 - 1] : i;

    float s = 0.f;
    floatx2 acc2[4] = {};

    for (int base = 0; base < total; base += 2) {
        unsigned g_nxt[4];
        *(uint4*)g_nxt = *(const uint4*)(xlr + ((unsigned)src_n * 512u + f));
        int t2 = base + 4 + half;
        int src_n2 = (t2 < total) ? col[e0 + t2 - 1] : i;
        bool valid = (base + half) < total;
        floatx2 xv[4], l2 = {0.f, 0.f};
        #pragma unroll
        for (int k = 0; k < 4; k++) {
            xv[k] = cvt2(g_cur[k]);
            floatx2 u = xv[k] + xrv[k];                    // v_pk_add_f32
            floatx2 lr = __builtin_elementwise_max(u, u * c02);  // leaky: pk_mul + pk_max
            l2 += lr * attv[k];                            // v_pk_fma_f32 (att * log2e)
        }
        float l = l2.x + l2.y;
        l = dpp_add<0xB1>(l);     // xor1 within quad
        l = dpp_add<0x4E>(l);     // xor2 within quad
        l = dpp_add<0x141>(l);    // cross-quad within 8-lane group
        float p;
        asm("v_exp_f32 %0, %1" : "=v"(p) : "v"(l));   // 2^(logit*log2e) = e^logit
        p = valid ? p : 0.f;
        s += p;
        floatx2 p2 = {p, p};
        #pragma unroll
        for (int k = 0; k < 4; k++) acc2[k] += p2 * xv[k];   // v_pk_fma_f32
        #pragma unroll
        for (int k = 0; k < 4; k++) g_cur[k] = g_nxt[k];
        src_n = src_n2;
    }

    // combine the two halves
    s += __shfl_xor(s, 32, 64);
    #pragma unroll
    for (int k = 0; k < 4; k++) {
        acc2[k].x += __shfl_xor(acc2[k].x, 32, 64);
        acc2[k].y += __shfl_xor(acc2[k].y, 32, 64);
    }

    if (half == 0) {
        float inv = 1.0f / (s + 1e-16f);
        bf16 ov[8];
        #pragma unroll
        for (int k = 0; k < 4; k++) {
            float v0 = acc2[k].x * inv + bias[f + 2 * k];
            float v1 = acc2[k].y * inv + bias[f + 2 * k + 1];
            if (do_gelu) { v0 = gelu_f(v0); v1 = gelu_f(v1); }
            ov[2 * k]     = f2b(v0);
            ov[2 * k + 1] = f2b(v1);
        }
        *(short8*)(out + ((unsigned)i * 256u + f)) = *(const short8*)ov;
    }
}

// ---------------- shared head-layer body (block = one (graph, 64-col chunk)) ----------------
__device__ __forceinline__ void head_body(const bf16* __restrict__ inB,
                                          const float* __restrict__ inF,
                                          const float* __restrict__ W,
                                          const float* __restrict__ bias,
                                          float* __restrict__ out,
                                          int K, int N, long long row_stride, int act,
                                          int g, int chunk, float* zin, float* red) {
    int t = threadIdx.x;
    int nc = t & 63;
    int kq = t >> 6;
    int n = chunk * 64 + nc;
    for (int k = t; k < K; k += 256)
        zin[k] = inB ? b2f(inB[(size_t)g * row_stride + k])
                     : inF[(size_t)g * row_stride + k];
    __syncthreads();
    const int klen = K >> 2;
    const int kb = kq * klen;
    float acc = 0.f;
    #pragma unroll 8
    for (int k = 0; k < klen; k++)
        acc = fmaf(zin[kb + k], W[(size_t)(kb + k) * N + n], acc);
    red[t] = acc;
    __syncthreads();
    if (kq == 0) {
        float v = red[nc] + red[nc + 64] + red[nc + 128] + red[nc + 192] + bias[n];
        if (act) v = gelu_f(v);
        out[(size_t)g * N + n] = v;
    }
}

// ---------------- fused: pool stage 1 (blocks 0..511) + head lin1 (512..1535) ----------------
__global__ __launch_bounds__(256) void k_pe1(const bf16* __restrict__ hb,
                                             float* __restrict__ part,
                                             const float* __restrict__ lin1w,
                                             const float* __restrict__ lin1b,
                                             float* __restrict__ t1, int PG) {
    __shared__ float zin[256];
    __shared__ float red[256];
    int bx = blockIdx.x;
    if (bx < 512) {
        int g = bx >> 3, p = bx & 7, c = threadIdx.x;
        int rows_per = PG / 8;
        const bf16* base = hb + ((size_t)g * PG + (size_t)p * rows_per) * 256;
        float acc = 0.f;
        for (int r = 0; r < rows_per; r++) acc += b2f(base[(size_t)r * 256 + c]);
        part[((size_t)g * 8 + p) * 256 + c] = acc;
    } else {
        int b = bx - 512;
        head_body(hb, nullptr, lin1w, lin1b, t1, 256, 1024,
                  (long long)PG * 256, 1, b >> 4, b & 15, zin, red);
    }
}

// ---------------- fused: pool stage 2 (blocks 0..63) + head lin2 (64..319) ----------------
__global__ __launch_bounds__(256) void k_pe2(const float* __restrict__ part,
                                             float* __restrict__ outPool, int PG,
                                             const float* __restrict__ t1,
                                             const float* __restrict__ lin2w,
                                             const float* __restrict__ lin2b,
                                             float* __restrict__ t2) {
    __shared__ float zin[1024];
    __shared__ float red[256];
    int bx = blockIdx.x;
    if (bx < 64) {
        int g = bx, c = threadIdx.x;
        float acc = 0.f;
        for (int p = 0; p < 8; p++) acc += part[((size_t)g * 8 + p) * 256 + c];
        outPool[g * 256 + c] = acc / (float)PG;
    } else {
        int b = bx - 64;
        head_body(nullptr, t1, lin2w, lin2b, t2, 1024, 256,
                  1024, 0, b >> 2, b & 3, zin, red);
    }
}

// ---------------- final head layer ----------------
__global__ __launch_bounds__(256) void k_fin(const float* __restrict__ t2,
                                             const float* __restrict__ finw,
                                             const float* __restrict__ finb,
                                             float* __restrict__ out) {
    __shared__ float zin[256];
    __shared__ float red[256];
    head_body(nullptr, t2, finw, finb, out, 256, 512,
              256, 0, blockIdx.x, blockIdx.y, zin, red);
}

extern "C" void kernel_launch(void* const* d_in, const int* in_sizes, int n_in,
                              void* d_out, int out_size, void* d_ws, size_t ws_size,
                              hipStream_t stream) {
    const float* x     = (const float*)d_in[0];
    const int*   ei    = (const int*)d_in[1];
    const float* w1_l  = (const float*)d_in[4];
    const float* b1_l  = (const float*)d_in[5];
    const float* w1_r  = (const float*)d_in[6];
    const float* b1_r  = (const float*)d_in[7];
    const float* att1  = (const float*)d_in[8];
    const float* bias1 = (const float*)d_in[9];
    const float* w2_l  = (const float*)d_in[10];
    const float* b2_l  = (const float*)d_in[11];
    const float* w2_r  = (const float*)d_in[12];
    const float* b2_r  = (const float*)d_in[13];
    const float* att2  = (const float*)d_in[14];
    const float* bias2 = (const float*)d_in[15];
    const float* lin1w = (const float*)d_in[16];
    const float* lin1b = (const float*)d_in[17];
    const float* lin2w = (const float*)d_in[18];
    const float* lin2b = (const float*)d_in[19];
    const float* finw  = (const float*)d_in[20];
    const float* finb  = (const float*)d_in[21];

    const int N  = in_sizes[0] / 256;   // 32768
    const int E  = in_sizes[1] / 2;     // 524288
    const int NG = 64;
    const int PG = N / NG;              // 512

    // workspace layout (~54.5 MiB)
    char* ws = (char*)d_ws;
    size_t off = 0;
    bf16* xlr = (bf16*)(ws + off); off += (size_t)N * 512 * 2;    // 32 MiB [xl|xr]
    bf16* hb  = (bf16*)(ws + off); off += (size_t)N * 256 * 2;    // 16 MiB (h1 then h2)
    bf16* wt  = (bf16*)(ws + off); off += 2 * 512 * 256 * 2;      // 512 KiB both layers' Wt
    int* row_ptr = (int*)(ws + off); off += (size_t)(N + 4) * 4;
    int* cnt     = (int*)(ws + off); off += (size_t)N * 4;
    int* col     = (int*)(ws + off); off += (size_t)E * 4;
    int* rank    = (int*)(ws + off); off += (size_t)E * 4;        // edge rank within dst
    float* pws   = (float*)(ws + off); off += (size_t)NG * 8 * 256 * 4;  // pool partials
    float* t1    = (float*)(ws + off); off += (size_t)NG * 1024 * 4;
    float* t2    = (float*)(ws + off); off += (size_t)NG * 256 * 4;

    // bf16 copy of x aliases hb: dead until k_agg writes h1 (strictly after GEMM1 reads xb)
    bf16* xb = hb;

    const int* srcv = ei;
    const int* dstv = ei + E;

    // --- CSR count+rank + weight transposes + x->bf16 (one launch) ---
    hipMemsetAsync(cnt, 0, (size_t)N * 4, stream);
    k_count_tr<<<512 + 1024 + 1024, 256, 0, stream>>>(dstv, cnt, E,
                                                      w1_l, w1_r, w2_l, w2_r, wt, x, xb,
                                                      rank);
    k_scan<<<1, 1024, 0, stream>>>(cnt, row_ptr, N);

    // --- scatter (atomic-free) + layer-1 GEMM (one union launch) ---
    k_scatter_gemm<<<512 + 1024, 256, 0, stream>>>(srcv, dstv, row_ptr, rank, col, E,
                                                   xb, wt, b1_l, b1_r, xlr, 256);
    k_agg<<<N / 2, 128, 0, stream>>>(xlr, att1, row_ptr, col, bias1, hb, 1);  // + GELU

    // --- layer 2 (A = h1 bf16) ---
    dim3 gg(4, N / 128);
    k_gemm2<<<gg, 256, 0, stream>>>(hb, wt + 512 * 256, b2_l, b2_r, xlr, 256);
    k_agg<<<N / 2, 128, 0, stream>>>(xlr, att2, row_ptr, col, bias2, hb, 0);  // h2

    float* outp = (float*)d_out;
    // --- pool1 + head lin1 (one launch) ---
    k_pe1<<<512 + 1024, 256, 0, stream>>>(hb, pws, lin1w, lin1b, t1, PG);
    // --- pool2 (-> d_out[64*512..]) + head lin2 (one launch) ---
    k_pe2<<<64 + 256, 256, 0, stream>>>(pws, outp + 64 * 512, PG, t1, lin2w, lin2b, t2);
    // --- final head layer -> d_out[0..64*512) ---
    dim3 gf(NG, 512 / 64);
    k_fin<<<gf, 256, 0, stream>>>(t2, finw, finb, outp);
}